// Round 1
// baseline (680.590 us; speedup 1.0000x reference)
//
#include <hip/hip_runtime.h>
#include <cstdint>
#include <cstddef>

// ---------------------------------------------------------------- types
typedef __bf16 bf16x8 __attribute__((ext_vector_type(8)));
typedef float  f32x4  __attribute__((ext_vector_type(4)));

#define LDS_AS __attribute__((address_space(3)))
#define GLB_AS __attribute__((address_space(1)))

static __device__ __forceinline__ unsigned short f2bf(float f) {
    unsigned int u = __float_as_uint(f);
    u += 0x7fffu + ((u >> 16) & 1u);   // RNE; inputs are finite/normal
    return (unsigned short)(u >> 16);
}

// ---------------------------------------------------------------- fp32 -> bf16
__global__ __launch_bounds__(256) void cvt_f32_bf16(const float* __restrict__ in,
                                                    unsigned short* __restrict__ out, int n4) {
    int stride = gridDim.x * blockDim.x;
    for (int i = blockIdx.x * blockDim.x + threadIdx.x; i < n4; i += stride) {
        float4 f = reinterpret_cast<const float4*>(in)[i];
        ushort4 u;
        u.x = f2bf(f.x); u.y = f2bf(f.y); u.z = f2bf(f.z); u.w = f2bf(f.w);
        reinterpret_cast<ushort4*>(out)[i] = u;
    }
}

// ---------------------------------------------------------------- PE frequency table
__global__ void divtab_kernel(float* __restrict__ dtab) {
    int i = threadIdx.x;                       // 256 threads
    dtab[i] = expf((float)(2 * i) * (-9.210340371976184f / 512.0f)); // exp(2i * -ln(1e4)/512)
}

// ---------------------------------------------------------------- GEMM  C = A @ B^T
// A: M x K bf16 (lda), B: N x K bf16 (ldb).  m97 structure: 128x128 tile, BK=32,
// 4 waves (2x2 of 64x64), global_load_lds width 16, single LDS buffer, 2 barriers/K-step.
// EPI: 0 = relu+bias -> bf16; 1 = bias -> bf16; 2 = bias+posenc -> bf16 AND f32; 3 = *scale -> f32
template<int EPI>
__global__ __launch_bounds__(256) void gemm_bt(
    const unsigned short* __restrict__ A, int lda,
    const unsigned short* __restrict__ B, int ldb,
    int M, int N, int K,
    const float* __restrict__ bias,
    unsigned short* __restrict__ Cb, float* __restrict__ Cf, int ldc,
    float scale, const float* __restrict__ dtab)
{
    __shared__ unsigned short ldsA[128 * 32];
    __shared__ unsigned short ldsB[128 * 32];

    const int nbn = N >> 7;
    const int bm = blockIdx.x / nbn, bn = blockIdx.x % nbn;
    const int t = threadIdx.x;
    const int lane = t & 63, wid = t >> 6;
    const int wr = wid >> 1, wc = wid & 1;
    const int l15 = lane & 15, l4 = lane >> 4;

    // staging: thread t loads rows (t>>2) and (t>>2)+64, k-offset (t&3)*8 (16B each)
    const unsigned short* ga0 = A + (size_t)(bm * 128 + (t >> 2)) * lda + (t & 3) * 8;
    const unsigned short* gb0 = B + (size_t)(bn * 128 + (t >> 2)) * ldb + (t & 3) * 8;
    const size_t a64 = (size_t)64 * lda, b64 = (size_t)64 * ldb;
    LDS_AS void* laD0 = (LDS_AS void*)(&ldsA[wid * 512]);
    LDS_AS void* laD1 = (LDS_AS void*)(&ldsA[2048 + wid * 512]);
    LDS_AS void* lbD0 = (LDS_AS void*)(&ldsB[wid * 512]);
    LDS_AS void* lbD1 = (LDS_AS void*)(&ldsB[2048 + wid * 512]);

    // fragment read pointers: A row = wr*64 + mi*16 + l15, k = l4*8
    const bf16x8* pa = (const bf16x8*)&ldsA[(wr * 64 + l15) * 32 + l4 * 8];
    const bf16x8* pb = (const bf16x8*)&ldsB[(wc * 64 + l15) * 32 + l4 * 8];

    f32x4 acc[4][4];
    const f32x4 z = {0.f, 0.f, 0.f, 0.f};
#pragma unroll
    for (int i = 0; i < 4; i++)
#pragma unroll
        for (int j = 0; j < 4; j++) acc[i][j] = z;

    const int nk = K >> 5;
    for (int kt = 0; kt < nk; ++kt) {
        const unsigned short* ga = ga0 + kt * 32;
        const unsigned short* gb = gb0 + kt * 32;
        __builtin_amdgcn_global_load_lds((const GLB_AS void*)ga,         laD0, 16, 0, 0);
        __builtin_amdgcn_global_load_lds((const GLB_AS void*)(ga + a64), laD1, 16, 0, 0);
        __builtin_amdgcn_global_load_lds((const GLB_AS void*)gb,         lbD0, 16, 0, 0);
        __builtin_amdgcn_global_load_lds((const GLB_AS void*)(gb + b64), lbD1, 16, 0, 0);
        __syncthreads();   // drains vmcnt -> staged tile visible

        bf16x8 af[4], bfr[4];
#pragma unroll
        for (int mi = 0; mi < 4; mi++) af[mi]  = pa[mi * 64];   // +16 rows = 64 vec16
#pragma unroll
        for (int ni = 0; ni < 4; ni++) bfr[ni] = pb[ni * 64];
#pragma unroll
        for (int mi = 0; mi < 4; mi++)
#pragma unroll
            for (int ni = 0; ni < 4; ni++)
                acc[mi][ni] = __builtin_amdgcn_mfma_f32_16x16x32_bf16(af[mi], bfr[ni], acc[mi][ni], 0, 0, 0);
        __syncthreads();   // LDS consumed, safe to restage
    }

    const int row0 = bm * 128 + wr * 64;
    const int col0 = bn * 128 + wc * 64;
#pragma unroll
    for (int mi = 0; mi < 4; mi++) {
#pragma unroll
        for (int ni = 0; ni < 4; ni++) {
            f32x4 c = acc[mi][ni];
            const int col = col0 + ni * 16 + l15;
            float bv = 0.f, dv = 0.f;
            if (EPI != 3) bv = bias[col];
            if (EPI == 2) dv = dtab[col >> 1];
#pragma unroll
            for (int r = 0; r < 4; r++) {
                const int row = row0 + mi * 16 + l4 * 4 + r;
                float v = c[r] + bv;
                if (EPI == 0) v = fmaxf(v, 0.f);
                if (EPI == 2) {
                    float ang = (float)row * dv;
                    v += (col & 1) ? cosf(ang) : sinf(ang);
                }
                if (EPI == 3) {
                    Cf[(size_t)row * ldc + col] = v * scale;
                } else {
                    Cb[(size_t)row * ldc + col] = f2bf(v);
                    if (EPI == 2) Cf[(size_t)row * ldc + col] = v;
                }
            }
        }
    }
}

// ---------------------------------------------------------------- v column (fp32)
__global__ __launch_bounds__(256) void vcol_kernel(const float* __restrict__ Hf,
                                                   const float* __restrict__ ipw,
                                                   const float* __restrict__ ipb,
                                                   float* __restrict__ v) {
    const int row = blockIdx.x * 4 + (threadIdx.x >> 6);
    const int lane = threadIdx.x & 63;
    const float* w = ipw + (size_t)1535 * 512;
    const float* h = Hf + (size_t)row * 512;
    float s = 0.f;
    for (int k = lane; k < 512; k += 64) s += h[k] * w[k];
#pragma unroll
    for (int off = 32; off; off >>= 1) s += __shfl_down(s, off);
    if (lane == 0) v[row] = s + ipb[1535];
}

// ---------------------------------------------------------------- attention rows 3584..4095
// out[r] = sum_i (softmax(S1)[i] - lam*softmax(S2)[i]) * v[i] + sum_{i>3584+r} v[i]
__global__ __launch_bounds__(256) void attn_rows(const float* __restrict__ S1,
                                                 const float* __restrict__ S2,
                                                 const float* __restrict__ v,
                                                 const float* __restrict__ lamp,
                                                 float* __restrict__ out) {
    const int r = blockIdx.x;
    const int tid = threadIdx.x, lane = tid & 63, wid = tid >> 6;
    const float* s1 = S1 + (size_t)r * 4096;
    const float* s2 = S2 + (size_t)r * 4096;
    __shared__ float red[4][8];

    float m1 = -1e30f, m2 = -1e30f;
    for (int i = tid; i < 4096; i += 256) {
        m1 = fmaxf(m1, s1[i]);
        m2 = fmaxf(m2, s2[i]);
    }
#pragma unroll
    for (int off = 32; off; off >>= 1) {
        m1 = fmaxf(m1, __shfl_down(m1, off));
        m2 = fmaxf(m2, __shfl_down(m2, off));
    }
    if (lane == 0) { red[wid][0] = m1; red[wid][1] = m2; }
    __syncthreads();
    m1 = fmaxf(fmaxf(red[0][0], red[1][0]), fmaxf(red[2][0], red[3][0]));
    m2 = fmaxf(fmaxf(red[0][1], red[1][1]), fmaxf(red[2][1], red[3][1]));

    const int gj = 3584 + r;
    float e1 = 0.f, e2 = 0.f, d1 = 0.f, d2 = 0.f, cs = 0.f;
    for (int i = tid; i < 4096; i += 256) {
        float p1 = expf(s1[i] - m1);
        float p2 = expf(s2[i] - m2);
        float vv = v[i];
        e1 += p1; e2 += p2; d1 += p1 * vv; d2 += p2 * vv;
        if (i > gj) cs += vv;
    }
#pragma unroll
    for (int off = 32; off; off >>= 1) {
        e1 += __shfl_down(e1, off); e2 += __shfl_down(e2, off);
        d1 += __shfl_down(d1, off); d2 += __shfl_down(d2, off);
        cs += __shfl_down(cs, off);
    }
    __syncthreads();
    if (lane == 0) {
        red[wid][0] = e1; red[wid][1] = e2; red[wid][2] = d1; red[wid][3] = d2; red[wid][4] = cs;
    }
    __syncthreads();
    if (tid == 0) {
        e1 = red[0][0] + red[1][0] + red[2][0] + red[3][0];
        e2 = red[0][1] + red[1][1] + red[2][1] + red[3][1];
        d1 = red[0][2] + red[1][2] + red[2][2] + red[3][2];
        d2 = red[0][3] + red[1][3] + red[2][3] + red[3][3];
        cs = red[0][4] + red[1][4] + red[2][4] + red[3][4];
        out[r] = d1 / e1 - lamp[0] * (d2 / e2) + cs;
    }
}

// ---------------------------------------------------------------- fp32 mat-vec, wave per output
template<int RELU>
__global__ __launch_bounds__(256) void matvec(const float* __restrict__ W, const float* __restrict__ x,
                                              const float* __restrict__ b, float* __restrict__ y,
                                              int N, int K) {
    const int o = blockIdx.x * 4 + (threadIdx.x >> 6);
    const int lane = threadIdx.x & 63;
    if (o >= N) return;
    const float* w = W + (size_t)o * K;
    float s = 0.f;
    for (int k = lane; k < K; k += 64) s += w[k] * x[k];
#pragma unroll
    for (int off = 32; off; off >>= 1) s += __shfl_down(s, off);
    if (lane == 0) y[o] = RELU ? fmaxf(s + b[o], 0.f) : (s + b[o]);
}

// ---------------------------------------------------------------- softmax over 256 logits
__global__ __launch_bounds__(256) void softmax256(const float* __restrict__ lg, float* __restrict__ out) {
    const int tid = threadIdx.x, lane = tid & 63, wid = tid >> 6;
    __shared__ float rm[4], rs[4];
    float l = lg[tid];
    float m = l;
#pragma unroll
    for (int off = 32; off; off >>= 1) m = fmaxf(m, __shfl_down(m, off));
    if (lane == 0) rm[wid] = m;
    __syncthreads();
    m = fmaxf(fmaxf(rm[0], rm[1]), fmaxf(rm[2], rm[3]));
    float e = expf(l - m);
    float s = e;
#pragma unroll
    for (int off = 32; off; off >>= 1) s += __shfl_down(s, off);
    if (lane == 0) rs[wid] = s;
    __syncthreads();
    s = rs[0] + rs[1] + rs[2] + rs[3];
    out[tid] = e / s;
}

// ---------------------------------------------------------------- launch
extern "C" void kernel_launch(void* const* d_in, const int* in_sizes, int n_in,
                              void* d_out, int out_size, void* d_ws, size_t ws_size,
                              hipStream_t stream) {
    const float* x      = (const float*)d_in[0];
    const float* enc_w1 = (const float*)d_in[1];
    const float* enc_b1 = (const float*)d_in[2];
    const float* enc_w2 = (const float*)d_in[3];
    const float* enc_b2 = (const float*)d_in[4];
    const float* enc_w3 = (const float*)d_in[5];
    const float* enc_b3 = (const float*)d_in[6];
    const float* enc_w4 = (const float*)d_in[7];
    const float* enc_b4 = (const float*)d_in[8];
    const float* ipw    = (const float*)d_in[9];
    const float* ipb    = (const float*)d_in[10];
    const float* opw    = (const float*)d_in[11];
    const float* opb    = (const float*)d_in[12];
    const float* lam    = (const float*)d_in[13];
    const float* aw1    = (const float*)d_in[14];
    const float* ab1    = (const float*)d_in[15];
    const float* aw2    = (const float*)d_in[16];
    const float* ab2    = (const float*)d_in[17];
    const float* aw3    = (const float*)d_in[18];
    const float* ab3    = (const float*)d_in[19];

    char* ws = (char*)d_ws;
    const size_t MB = 1ull << 20;
    unsigned short* bufA = (unsigned short*)(ws);             // 32MB: Xb then C2b
    unsigned short* bufB = (unsigned short*)(ws + 32 * MB);   // 16MB: C1b then C3b
    float* S1            = (float*)(ws + 32 * MB);            // 8MB (after C3b dead)
    float* S2            = (float*)(ws + 40 * MB);            // 8MB
    unsigned short* Wb   = (unsigned short*)(ws + 48 * MB);   // 16MB: per-layer weight bf16
    unsigned short* IPb  = (unsigned short*)(ws + 64 * MB);   // 1.5MB
    unsigned short* Hb   = (unsigned short*)(ws + 66 * MB);   // 4MB
    float* Hf            = (float*)(ws + 70 * MB);            // 8MB
    unsigned short* Kb   = (unsigned short*)(ws + 78 * MB);   // 4MB
    unsigned short* Qb   = (unsigned short*)(ws + 82 * MB);   // 0.5MB
    float* vcol          = (float*)(ws + 83 * MB);
    float* dtab          = (float*)(ws + 83 * MB + 64 * 1024);
    float* attnv         = (float*)(ws + 83 * MB + 128 * 1024);
    float* hh            = (float*)(ws + 83 * MB + 192 * 1024);
    float* h1            = (float*)(ws + 83 * MB + 256 * 1024);
    float* h2            = (float*)(ws + 83 * MB + 320 * 1024);
    float* lg            = (float*)(ws + 83 * MB + 384 * 1024);

    auto cvt = [&](const float* in, unsigned short* outp, int n) {
        int n4 = n >> 2;
        int blocks = (n4 + 255) / 256;
        if (blocks > 2048) blocks = 2048;
        cvt_f32_bf16<<<dim3(blocks), dim3(256), 0, stream>>>(in, outp, n4);
    };

    divtab_kernel<<<dim3(1), dim3(256), 0, stream>>>(dtab);

    // ---- encoder (bf16 MFMA, fused relu/bias/PE epilogues) ----
    cvt(x, bufA, 4096 * 1024);
    cvt(enc_w1, Wb, 2048 * 1024);
    gemm_bt<0><<<dim3(32 * 16), dim3(256), 0, stream>>>(bufA, 1024, Wb, 1024, 4096, 2048, 1024,
                                                        enc_b1, bufB, nullptr, 2048, 1.f, nullptr);
    cvt(enc_w2, Wb, 4096 * 2048);
    gemm_bt<0><<<dim3(32 * 32), dim3(256), 0, stream>>>(bufB, 2048, Wb, 2048, 4096, 4096, 2048,
                                                        enc_b2, bufA, nullptr, 4096, 1.f, nullptr);
    cvt(enc_w3, Wb, 2048 * 4096);
    gemm_bt<0><<<dim3(32 * 16), dim3(256), 0, stream>>>(bufA, 4096, Wb, 4096, 4096, 2048, 4096,
                                                        enc_b3, bufB, nullptr, 2048, 1.f, nullptr);
    cvt(enc_w4, Wb, 512 * 2048);
    gemm_bt<2><<<dim3(32 * 4), dim3(256), 0, stream>>>(bufB, 2048, Wb, 2048, 4096, 512, 2048,
                                                       enc_b4, Hb, Hf, 512, 1.f, dtab);

    // ---- projections (K full, Q only rows 3584.., v one column) ----
    cvt(ipw, IPb, 1536 * 512);
    gemm_bt<1><<<dim3(32 * 4), dim3(256), 0, stream>>>(Hb, 512, IPb + 512 * 512, 512, 4096, 512, 512,
                                                       ipb + 512, Kb, nullptr, 512, 1.f, nullptr);
    gemm_bt<1><<<dim3(4 * 4), dim3(256), 0, stream>>>(Hb + (size_t)3584 * 512, 512, IPb, 512, 512, 512, 512,
                                                      ipb, Qb, nullptr, 512, 1.f, nullptr);
    vcol_kernel<<<dim3(1024), dim3(256), 0, stream>>>(Hf, ipw, ipb, vcol);

    // ---- scores (512 x 4096, two heads) ----
    const float rs2 = 0.70710678118654752f;
    gemm_bt<3><<<dim3(4 * 32), dim3(256), 0, stream>>>(Qb, 512, Kb, 512, 512, 4096, 256,
                                                       nullptr, nullptr, S1, 4096, rs2, nullptr);
    gemm_bt<3><<<dim3(4 * 32), dim3(256), 0, stream>>>(Qb + 256, 512, Kb + 256, 512, 512, 4096, 256,
                                                       nullptr, nullptr, S2, 4096, rs2, nullptr);

    // ---- softmax + diff + causal + v-dot ----
    attn_rows<<<dim3(512), dim3(256), 0, stream>>>(S1, S2, vcol, lam, attnv);

    // ---- fp32 tail (single row) ----
    matvec<0><<<dim3(128), dim3(256), 0, stream>>>(opw, attnv, opb, hh, 512, 512);
    matvec<1><<<dim3(256), dim3(256), 0, stream>>>(aw1, hh, ab1, h1, 1024, 512);
    matvec<1><<<dim3(512), dim3(256), 0, stream>>>(aw2, h1, ab2, h2, 2048, 1024);
    matvec<0><<<dim3(64), dim3(256), 0, stream>>>(aw3, h2, ab3, lg, 256, 2048);
    softmax256<<<dim3(1), dim3(256), 0, stream>>>(lg, (float*)d_out);
}

// Round 2
// 655.055 us; speedup vs baseline: 1.0390x; 1.0390x over previous
//
#include <hip/hip_runtime.h>
#include <cstdint>
#include <cstddef>

// ---------------------------------------------------------------- types
typedef __bf16 bf16x8 __attribute__((ext_vector_type(8)));
typedef float  f32x4  __attribute__((ext_vector_type(4)));

#define LDS_AS __attribute__((address_space(3)))
#define GLB_AS __attribute__((address_space(1)))

static __device__ __forceinline__ unsigned short f2bf(float f) {
    unsigned int u = __float_as_uint(f);
    u += 0x7fffu + ((u >> 16) & 1u);   // RNE; inputs are finite/normal
    return (unsigned short)(u >> 16);
}

// ---------------------------------------------------------------- fp32 -> bf16
__global__ __launch_bounds__(256) void cvt_f32_bf16(const float* __restrict__ in,
                                                    unsigned short* __restrict__ out, int n4) {
    int stride = gridDim.x * blockDim.x;
    for (int i = blockIdx.x * blockDim.x + threadIdx.x; i < n4; i += stride) {
        float4 f = reinterpret_cast<const float4*>(in)[i];
        ushort4 u;
        u.x = f2bf(f.x); u.y = f2bf(f.y); u.z = f2bf(f.z); u.w = f2bf(f.w);
        reinterpret_cast<ushort4*>(out)[i] = u;
    }
}

// ---------------------------------------------------------------- PE frequency table
__global__ void divtab_kernel(float* __restrict__ dtab) {
    int i = threadIdx.x;                       // 256 threads
    dtab[i] = expf((float)(2 * i) * (-9.210340371976184f / 512.0f));
}

// ================================================================ 256x256 8-phase GEMM
// C = A @ B^T.  BM=BN=256, BK=32, 512 threads = 8 waves (2M x 4N), per-wave 128x64.
// 4-slot round-robin LDS buffers (4 x (A16K+B16K) = 128KiB). Tile t+2 staged during
// tile t (2 global_load_lds per phase). vmcnt(4) once per K-tile, never 0 in loop.
// LDS XOR swizzle: slot ^= (row>>1)&3, applied on read AND (inverse) on global source.
// EPI: 0 = relu+bias -> bf16
template<int EPI>
__global__ __launch_bounds__(512, 2) void gemm256_bt(
    const unsigned short* __restrict__ A, int lda,
    const unsigned short* __restrict__ B, int ldb,
    int M, int N, int K,
    const float* __restrict__ bias,
    unsigned short* __restrict__ Cb, int ldc)
{
    __shared__ __align__(16) unsigned short lds[4][2][8192];  // [buf][A|B][256*32]

    const int nbn = N >> 8;
    int wg = blockIdx.x;
    {   // bijective XCD swizzle (all grids here are multiples of 8)
        int q = gridDim.x >> 3;
        wg = (wg & 7) * q + (wg >> 3);
    }
    const int bm = wg / nbn, bn = wg % nbn;

    const int t = threadIdx.x;
    const int lane = t & 63, wid = t >> 6;
    const int wr = wid >> 2, wc = wid & 3;      // wave grid 2 x 4
    const int l15 = lane & 15, l4 = lane >> 4;

    // ---- staging source (inverse-swizzled k-slot) ----
    const int sr = t >> 2;                       // row 0..127 within half
    const int ss = (t & 3) ^ ((sr >> 1) & 3);    // pre-swizzled k-slot
    const unsigned short* gA0 = A + (size_t)(bm * 256 + sr      ) * lda + ss * 8;
    const unsigned short* gA1 = A + (size_t)(bm * 256 + sr + 128) * lda + ss * 8;
    const unsigned short* gB0 = B + (size_t)(bn * 256 + sr      ) * ldb + ss * 8;
    const unsigned short* gB1 = B + (size_t)(bn * 256 + sr + 128) * ldb + ss * 8;

    // ---- swizzled ds_read base byte offsets ----
    const int rsw  = ((l4 ^ ((l15 >> 1) & 3)) << 4);       // swizzled 16B slot
    const int aoff = (wr * 128 + l15) * 64 + rsw;          // + mi*1024
    const int boff = (wc * 64  + l15) * 64 + rsw;          // + ni*1024

    f32x4 acc[8][4];
    const f32x4 z = {0.f, 0.f, 0.f, 0.f};
#pragma unroll
    for (int i = 0; i < 8; i++)
#pragma unroll
        for (int j = 0; j < 4; j++) acc[i][j] = z;

    const int nk = K >> 5;

#define STAGE_A(kt_) do { int b_ = (kt_) & 3;                                              \
        __builtin_amdgcn_global_load_lds((const GLB_AS void*)(gA0 + (kt_) * 32),           \
            (LDS_AS void*)&lds[b_][0][wid * 512], 16, 0, 0);                               \
        __builtin_amdgcn_global_load_lds((const GLB_AS void*)(gA1 + (kt_) * 32),           \
            (LDS_AS void*)&lds[b_][0][4096 + wid * 512], 16, 0, 0); } while (0)
#define STAGE_B(kt_) do { int b_ = (kt_) & 3;                                              \
        __builtin_amdgcn_global_load_lds((const GLB_AS void*)(gB0 + (kt_) * 32),           \
            (LDS_AS void*)&lds[b_][1][wid * 512], 16, 0, 0);                               \
        __builtin_amdgcn_global_load_lds((const GLB_AS void*)(gB1 + (kt_) * 32),           \
            (LDS_AS void*)&lds[b_][1][4096 + wid * 512], 16, 0, 0); } while (0)

    // ---- prologue: tiles 0 and 1 staged; tile 0 landed, tile 1 in flight ----
    STAGE_A(0); STAGE_B(0);
    STAGE_A(1); STAGE_B(1);
    asm volatile("s_waitcnt vmcnt(4)" ::: "memory");
    __builtin_amdgcn_s_barrier();
    __builtin_amdgcn_sched_barrier(0);

    for (int kt = 0; kt < nk; ++kt) {
        const int b = kt & 3;
        const LDS_AS char* abase = (const LDS_AS char*)&lds[b][0][0] + aoff;
        const LDS_AS char* bbase = (const LDS_AS char*)&lds[b][1][0] + boff;

        // ---------------- phase 0: mi 0..3 x ni 0..3 ----------------
        bf16x8 af[4], bfr[4];
#pragma unroll
        for (int i = 0; i < 4; ++i) af[i]  = *(const LDS_AS bf16x8*)(abase + i * 1024);
#pragma unroll
        for (int j = 0; j < 4; ++j) bfr[j] = *(const LDS_AS bf16x8*)(bbase + j * 1024);
        if (kt + 2 < nk) STAGE_A(kt + 2);
        __builtin_amdgcn_s_barrier();
        asm volatile("s_waitcnt lgkmcnt(0)" ::: "memory");
        __builtin_amdgcn_sched_barrier(0);
        __builtin_amdgcn_s_setprio(1);
#pragma unroll
        for (int i = 0; i < 4; ++i)
#pragma unroll
            for (int j = 0; j < 4; ++j)
                acc[i][j] = __builtin_amdgcn_mfma_f32_16x16x32_bf16(af[i], bfr[j], acc[i][j], 0, 0, 0);
        __builtin_amdgcn_s_setprio(0);
        __builtin_amdgcn_sched_barrier(0);
        __builtin_amdgcn_s_barrier();

        // ---------------- phase 1: mi 4..7 x ni 0..3 (B reused) ------
#pragma unroll
        for (int i = 0; i < 4; ++i) af[i] = *(const LDS_AS bf16x8*)(abase + 4096 + i * 1024);
        if (kt + 2 < nk) {
            STAGE_B(kt + 2);
            asm volatile("s_waitcnt vmcnt(4)" ::: "memory");   // tile kt+1 landed, kt+2 in flight
        } else {
            asm volatile("s_waitcnt vmcnt(0)" ::: "memory");   // epilogue drain
        }
        __builtin_amdgcn_s_barrier();
        asm volatile("s_waitcnt lgkmcnt(0)" ::: "memory");
        __builtin_amdgcn_sched_barrier(0);
        __builtin_amdgcn_s_setprio(1);
#pragma unroll
        for (int i = 0; i < 4; ++i)
#pragma unroll
            for (int j = 0; j < 4; ++j)
                acc[4 + i][j] = __builtin_amdgcn_mfma_f32_16x16x32_bf16(af[i], bfr[j], acc[4 + i][j], 0, 0, 0);
        __builtin_amdgcn_s_setprio(0);
        __builtin_amdgcn_sched_barrier(0);
        __builtin_amdgcn_s_barrier();
    }
#undef STAGE_A
#undef STAGE_B

    // ---------------- epilogue ----------------
    const int row0 = bm * 256 + wr * 128;
    const int col0 = bn * 256 + wc * 64;
#pragma unroll
    for (int mi = 0; mi < 8; mi++) {
#pragma unroll
        for (int ni = 0; ni < 4; ni++) {
            f32x4 c = acc[mi][ni];
            const int col = col0 + ni * 16 + l15;
            const float bv = bias[col];
#pragma unroll
            for (int r = 0; r < 4; r++) {
                const int row = row0 + mi * 16 + l4 * 4 + r;
                float v = c[r] + bv;
                if (EPI == 0) v = fmaxf(v, 0.f);
                Cb[(size_t)row * ldc + col] = f2bf(v);
            }
        }
    }
}

// ---------------------------------------------------------------- GEMM  C = A @ B^T (m97 128x128)
// EPI: 0 = relu+bias -> bf16; 1 = bias -> bf16; 2 = bias+posenc -> bf16 AND f32; 3 = *scale -> f32
template<int EPI>
__global__ __launch_bounds__(256) void gemm_bt(
    const unsigned short* __restrict__ A, int lda,
    const unsigned short* __restrict__ B, int ldb,
    int M, int N, int K,
    const float* __restrict__ bias,
    unsigned short* __restrict__ Cb, float* __restrict__ Cf, int ldc,
    float scale, const float* __restrict__ dtab)
{
    __shared__ unsigned short ldsA[128 * 32];
    __shared__ unsigned short ldsB[128 * 32];

    const int nbn = N >> 7;
    const int bm = blockIdx.x / nbn, bn = blockIdx.x % nbn;
    const int t = threadIdx.x;
    const int lane = t & 63, wid = t >> 6;
    const int wr = wid >> 1, wc = wid & 1;
    const int l15 = lane & 15, l4 = lane >> 4;

    const unsigned short* ga0 = A + (size_t)(bm * 128 + (t >> 2)) * lda + (t & 3) * 8;
    const unsigned short* gb0 = B + (size_t)(bn * 128 + (t >> 2)) * ldb + (t & 3) * 8;
    const size_t a64 = (size_t)64 * lda, b64 = (size_t)64 * ldb;
    LDS_AS void* laD0 = (LDS_AS void*)(&ldsA[wid * 512]);
    LDS_AS void* laD1 = (LDS_AS void*)(&ldsA[2048 + wid * 512]);
    LDS_AS void* lbD0 = (LDS_AS void*)(&ldsB[wid * 512]);
    LDS_AS void* lbD1 = (LDS_AS void*)(&ldsB[2048 + wid * 512]);

    const bf16x8* pa = (const bf16x8*)&ldsA[(wr * 64 + l15) * 32 + l4 * 8];
    const bf16x8* pb = (const bf16x8*)&ldsB[(wc * 64 + l15) * 32 + l4 * 8];

    f32x4 acc[4][4];
    const f32x4 z = {0.f, 0.f, 0.f, 0.f};
#pragma unroll
    for (int i = 0; i < 4; i++)
#pragma unroll
        for (int j = 0; j < 4; j++) acc[i][j] = z;

    const int nk = K >> 5;
    for (int kt = 0; kt < nk; ++kt) {
        const unsigned short* ga = ga0 + kt * 32;
        const unsigned short* gb = gb0 + kt * 32;
        __builtin_amdgcn_global_load_lds((const GLB_AS void*)ga,         laD0, 16, 0, 0);
        __builtin_amdgcn_global_load_lds((const GLB_AS void*)(ga + a64), laD1, 16, 0, 0);
        __builtin_amdgcn_global_load_lds((const GLB_AS void*)gb,         lbD0, 16, 0, 0);
        __builtin_amdgcn_global_load_lds((const GLB_AS void*)(gb + b64), lbD1, 16, 0, 0);
        __syncthreads();

        bf16x8 af[4], bfr[4];
#pragma unroll
        for (int mi = 0; mi < 4; mi++) af[mi]  = pa[mi * 64];
#pragma unroll
        for (int ni = 0; ni < 4; ni++) bfr[ni] = pb[ni * 64];
#pragma unroll
        for (int mi = 0; mi < 4; mi++)
#pragma unroll
            for (int ni = 0; ni < 4; ni++)
                acc[mi][ni] = __builtin_amdgcn_mfma_f32_16x16x32_bf16(af[mi], bfr[ni], acc[mi][ni], 0, 0, 0);
        __syncthreads();
    }

    const int row0 = bm * 128 + wr * 64;
    const int col0 = bn * 128 + wc * 64;
#pragma unroll
    for (int mi = 0; mi < 4; mi++) {
#pragma unroll
        for (int ni = 0; ni < 4; ni++) {
            f32x4 c = acc[mi][ni];
            const int col = col0 + ni * 16 + l15;
            float bv = 0.f, dv = 0.f;
            if (EPI != 3) bv = bias[col];
            if (EPI == 2) dv = dtab[col >> 1];
#pragma unroll
            for (int r = 0; r < 4; r++) {
                const int row = row0 + mi * 16 + l4 * 4 + r;
                float v = c[r] + bv;
                if (EPI == 0) v = fmaxf(v, 0.f);
                if (EPI == 2) {
                    float ang = (float)row * dv;
                    v += (col & 1) ? cosf(ang) : sinf(ang);
                }
                if (EPI == 3) {
                    Cf[(size_t)row * ldc + col] = v * scale;
                } else {
                    Cb[(size_t)row * ldc + col] = f2bf(v);
                    if (EPI == 2) Cf[(size_t)row * ldc + col] = v;
                }
            }
        }
    }
}

// ---------------------------------------------------------------- v column (fp32)
__global__ __launch_bounds__(256) void vcol_kernel(const float* __restrict__ Hf,
                                                   const float* __restrict__ ipw,
                                                   const float* __restrict__ ipb,
                                                   float* __restrict__ v) {
    const int row = blockIdx.x * 4 + (threadIdx.x >> 6);
    const int lane = threadIdx.x & 63;
    const float* w = ipw + (size_t)1535 * 512;
    const float* h = Hf + (size_t)row * 512;
    float s = 0.f;
    for (int k = lane; k < 512; k += 64) s += h[k] * w[k];
#pragma unroll
    for (int off = 32; off; off >>= 1) s += __shfl_down(s, off);
    if (lane == 0) v[row] = s + ipb[1535];
}

// ---------------------------------------------------------------- attention rows 3584..4095
__global__ __launch_bounds__(256) void attn_rows(const float* __restrict__ S1,
                                                 const float* __restrict__ S2,
                                                 const float* __restrict__ v,
                                                 const float* __restrict__ lamp,
                                                 float* __restrict__ out) {
    const int r = blockIdx.x;
    const int tid = threadIdx.x, lane = tid & 63, wid = tid >> 6;
    const float* s1 = S1 + (size_t)r * 4096;
    const float* s2 = S2 + (size_t)r * 4096;
    __shared__ float red[4][8];

    float m1 = -1e30f, m2 = -1e30f;
    for (int i = tid; i < 4096; i += 256) {
        m1 = fmaxf(m1, s1[i]);
        m2 = fmaxf(m2, s2[i]);
    }
#pragma unroll
    for (int off = 32; off; off >>= 1) {
        m1 = fmaxf(m1, __shfl_down(m1, off));
        m2 = fmaxf(m2, __shfl_down(m2, off));
    }
    if (lane == 0) { red[wid][0] = m1; red[wid][1] = m2; }
    __syncthreads();
    m1 = fmaxf(fmaxf(red[0][0], red[1][0]), fmaxf(red[2][0], red[3][0]));
    m2 = fmaxf(fmaxf(red[0][1], red[1][1]), fmaxf(red[2][1], red[3][1]));

    const int gj = 3584 + r;
    float e1 = 0.f, e2 = 0.f, d1 = 0.f, d2 = 0.f, cs = 0.f;
    for (int i = tid; i < 4096; i += 256) {
        float p1 = expf(s1[i] - m1);
        float p2 = expf(s2[i] - m2);
        float vv = v[i];
        e1 += p1; e2 += p2; d1 += p1 * vv; d2 += p2 * vv;
        if (i > gj) cs += vv;
    }
#pragma unroll
    for (int off = 32; off; off >>= 1) {
        e1 += __shfl_down(e1, off); e2 += __shfl_down(e2, off);
        d1 += __shfl_down(d1, off); d2 += __shfl_down(d2, off);
        cs += __shfl_down(cs, off);
    }
    __syncthreads();
    if (lane == 0) {
        red[wid][0] = e1; red[wid][1] = e2; red[wid][2] = d1; red[wid][3] = d2; red[wid][4] = cs;
    }
    __syncthreads();
    if (tid == 0) {
        e1 = red[0][0] + red[1][0] + red[2][0] + red[3][0];
        e2 = red[0][1] + red[1][1] + red[2][1] + red[3][1];
        d1 = red[0][2] + red[1][2] + red[2][2] + red[3][2];
        d2 = red[0][3] + red[1][3] + red[2][3] + red[3][3];
        cs = red[0][4] + red[1][4] + red[2][4] + red[3][4];
        out[r] = d1 / e1 - lamp[0] * (d2 / e2) + cs;
    }
}

// ---------------------------------------------------------------- fp32 mat-vec, wave per output
template<int RELU>
__global__ __launch_bounds__(256) void matvec(const float* __restrict__ W, const float* __restrict__ x,
                                              const float* __restrict__ b, float* __restrict__ y,
                                              int N, int K) {
    const int o = blockIdx.x * 4 + (threadIdx.x >> 6);
    const int lane = threadIdx.x & 63;
    if (o >= N) return;
    const float* w = W + (size_t)o * K;
    float s = 0.f;
    for (int k = lane; k < K; k += 64) s += w[k] * x[k];
#pragma unroll
    for (int off = 32; off; off >>= 1) s += __shfl_down(s, off);
    if (lane == 0) y[o] = RELU ? fmaxf(s + b[o], 0.f) : (s + b[o]);
}

// ---------------------------------------------------------------- softmax over 256 logits
__global__ __launch_bounds__(256) void softmax256(const float* __restrict__ lg, float* __restrict__ out) {
    const int tid = threadIdx.x, lane = tid & 63, wid = tid >> 6;
    __shared__ float rm[4], rs[4];
    float l = lg[tid];
    float m = l;
#pragma unroll
    for (int off = 32; off; off >>= 1) m = fmaxf(m, __shfl_down(m, off));
    if (lane == 0) rm[wid] = m;
    __syncthreads();
    m = fmaxf(fmaxf(rm[0], rm[1]), fmaxf(rm[2], rm[3]));
    float e = expf(l - m);
    float s = e;
#pragma unroll
    for (int off = 32; off; off >>= 1) s += __shfl_down(s, off);
    if (lane == 0) rs[wid] = s;
    __syncthreads();
    s = rs[0] + rs[1] + rs[2] + rs[3];
    out[tid] = e / s;
}

// ---------------------------------------------------------------- launch
extern "C" void kernel_launch(void* const* d_in, const int* in_sizes, int n_in,
                              void* d_out, int out_size, void* d_ws, size_t ws_size,
                              hipStream_t stream) {
    const float* x      = (const float*)d_in[0];
    const float* enc_w1 = (const float*)d_in[1];
    const float* enc_b1 = (const float*)d_in[2];
    const float* enc_w2 = (const float*)d_in[3];
    const float* enc_b2 = (const float*)d_in[4];
    const float* enc_w3 = (const float*)d_in[5];
    const float* enc_b3 = (const float*)d_in[6];
    const float* enc_w4 = (const float*)d_in[7];
    const float* enc_b4 = (const float*)d_in[8];
    const float* ipw    = (const float*)d_in[9];
    const float* ipb    = (const float*)d_in[10];
    const float* opw    = (const float*)d_in[11];
    const float* opb    = (const float*)d_in[12];
    const float* lam    = (const float*)d_in[13];
    const float* aw1    = (const float*)d_in[14];
    const float* ab1    = (const float*)d_in[15];
    const float* aw2    = (const float*)d_in[16];
    const float* ab2    = (const float*)d_in[17];
    const float* aw3    = (const float*)d_in[18];
    const float* ab3    = (const float*)d_in[19];

    char* ws = (char*)d_ws;
    const size_t MB = 1ull << 20;
    unsigned short* bufA = (unsigned short*)(ws);             // 32MB: Xb then C2b
    unsigned short* bufB = (unsigned short*)(ws + 32 * MB);   // 16MB: C1b then C3b
    float* S1            = (float*)(ws + 32 * MB);            // 8MB (after C3b dead)
    float* S2            = (float*)(ws + 40 * MB);            // 8MB
    unsigned short* Wb   = (unsigned short*)(ws + 48 * MB);   // 16MB: per-layer weight bf16
    unsigned short* IPb  = (unsigned short*)(ws + 64 * MB);   // 1.5MB
    unsigned short* Hb   = (unsigned short*)(ws + 66 * MB);   // 4MB
    float* Hf            = (float*)(ws + 70 * MB);            // 8MB
    unsigned short* Kb   = (unsigned short*)(ws + 78 * MB);   // 4MB
    unsigned short* Qb   = (unsigned short*)(ws + 82 * MB);   // 0.5MB
    float* vcol          = (float*)(ws + 83 * MB);
    float* dtab          = (float*)(ws + 83 * MB + 64 * 1024);
    float* attnv         = (float*)(ws + 83 * MB + 128 * 1024);
    float* hh            = (float*)(ws + 83 * MB + 192 * 1024);
    float* h1            = (float*)(ws + 83 * MB + 256 * 1024);
    float* h2            = (float*)(ws + 83 * MB + 320 * 1024);
    float* lg            = (float*)(ws + 83 * MB + 384 * 1024);

    auto cvt = [&](const float* in, unsigned short* outp, int n) {
        int n4 = n >> 2;
        int blocks = (n4 + 255) / 256;
        if (blocks > 2048) blocks = 2048;
        cvt_f32_bf16<<<dim3(blocks), dim3(256), 0, stream>>>(in, outp, n4);
    };

    divtab_kernel<<<dim3(1), dim3(256), 0, stream>>>(dtab);

    // ---- encoder (bf16 MFMA; big 3 on the 8-phase 256^2 kernel) ----
    cvt(x, bufA, 4096 * 1024);
    cvt(enc_w1, Wb, 2048 * 1024);
    gemm256_bt<0><<<dim3(16 * 8), dim3(512), 0, stream>>>(bufA, 1024, Wb, 1024, 4096, 2048, 1024,
                                                          enc_b1, bufB, 2048);
    cvt(enc_w2, Wb, 4096 * 2048);
    gemm256_bt<0><<<dim3(16 * 16), dim3(512), 0, stream>>>(bufB, 2048, Wb, 2048, 4096, 4096, 2048,
                                                           enc_b2, bufA, 4096);
    cvt(enc_w3, Wb, 2048 * 4096);
    gemm256_bt<0><<<dim3(16 * 8), dim3(512), 0, stream>>>(bufA, 4096, Wb, 4096, 4096, 2048, 4096,
                                                          enc_b3, bufB, 2048);
    cvt(enc_w4, Wb, 512 * 2048);
    gemm_bt<2><<<dim3(32 * 4), dim3(256), 0, stream>>>(bufB, 2048, Wb, 2048, 4096, 512, 2048,
                                                       enc_b4, Hb, Hf, 512, 1.f, dtab);

    // ---- projections (K full, Q only rows 3584.., v one column) ----
    cvt(ipw, IPb, 1536 * 512);
    gemm_bt<1><<<dim3(32 * 4), dim3(256), 0, stream>>>(Hb, 512, IPb + 512 * 512, 512, 4096, 512, 512,
                                                       ipb + 512, Kb, nullptr, 512, 1.f, nullptr);
    gemm_bt<1><<<dim3(4 * 4), dim3(256), 0, stream>>>(Hb + (size_t)3584 * 512, 512, IPb, 512, 512, 512, 512,
                                                      ipb, Qb, nullptr, 512, 1.f, nullptr);
    vcol_kernel<<<dim3(1024), dim3(256), 0, stream>>>(Hf, ipw, ipb, vcol);

    // ---- scores (512 x 4096, two heads) ----
    const float rs2 = 0.70710678118654752f;
    gemm_bt<3><<<dim3(4 * 32), dim3(256), 0, stream>>>(Qb, 512, Kb, 512, 512, 4096, 256,
                                                       nullptr, nullptr, S1, 4096, rs2, nullptr);
    gemm_bt<3><<<dim3(4 * 32), dim3(256), 0, stream>>>(Qb + 256, 512, Kb + 256, 512, 512, 4096, 256,
                                                       nullptr, nullptr, S2, 4096, rs2, nullptr);

    // ---- softmax + diff + causal + v-dot ----
    attn_rows<<<dim3(512), dim3(256), 0, stream>>>(S1, S2, vcol, lam, attnv);

    // ---- fp32 tail (single row) ----
    matvec<0><<<dim3(128), dim3(256), 0, stream>>>(opw, attnv, opb, hh, 512, 512);
    matvec<1><<<dim3(256), dim3(256), 0, stream>>>(aw1, hh, ab1, h1, 1024, 512);
    matvec<1><<<dim3(512), dim3(256), 0, stream>>>(aw2, h1, ab2, h2, 2048, 1024);
    matvec<0><<<dim3(64), dim3(256), 0, stream>>>(aw3, h2, ab3, lg, 256, 2048);
    softmax256<<<dim3(1), dim3(256), 0, stream>>>(lg, (float*)d_out);
}

// Round 5
// 608.135 us; speedup vs baseline: 1.1191x; 1.0772x over previous
//
#include <hip/hip_runtime.h>
#include <cstdint>
#include <cstddef>

// Round 5 = round 3 kernel, resubmitted (rounds 3 and 4 died in infra:
// container-acquire failure, then GPU capacity timeout; kernel never ran).

// ---------------------------------------------------------------- types
typedef __bf16 bf16x8 __attribute__((ext_vector_type(8)));
typedef float  f32x4  __attribute__((ext_vector_type(4)));

#define LDS_AS __attribute__((address_space(3)))
#define GLB_AS __attribute__((address_space(1)))

static __device__ __forceinline__ unsigned short f2bf(float f) {
    unsigned int u = __float_as_uint(f);
    u += 0x7fffu + ((u >> 16) & 1u);   // RNE; inputs are finite/normal
    return (unsigned short)(u >> 16);
}

// ---------------------------------------------------------------- fp32 -> bf16
__global__ __launch_bounds__(256) void cvt_f32_bf16(const float* __restrict__ in,
                                                    unsigned short* __restrict__ out, int n4) {
    int stride = gridDim.x * blockDim.x;
    for (int i = blockIdx.x * blockDim.x + threadIdx.x; i < n4; i += stride) {
        float4 f = reinterpret_cast<const float4*>(in)[i];
        ushort4 u;
        u.x = f2bf(f.x); u.y = f2bf(f.y); u.z = f2bf(f.z); u.w = f2bf(f.w);
        reinterpret_cast<ushort4*>(out)[i] = u;
    }
}

// ---------------------------------------------------------------- PE frequency table
__global__ void divtab_kernel(float* __restrict__ dtab) {
    int i = threadIdx.x;                       // 256 threads
    dtab[i] = expf((float)(2 * i) * (-9.210340371976184f / 512.0f));
}

// ================================================================ 256xNB 8-phase GEMM
// C = A @ B^T.  BM=256, BN=NB(256|128), BK=32, 512 threads = 8 waves (2M x 4N),
// per-wave 128 x NB/4.  4-slot round-robin LDS buffers; tile t+3 staged during tile t
// (A in phase 0, B in phase 1).  vmcnt leaves tiles t+2,t+3 in flight -> t+1 landed.
// Never drains vmcnt to 0 in the main loop.  ID only disambiguates profile names.
template<int EPI, int NB, int ID>
__global__ __launch_bounds__(512, 2) void gemm256_bt(
    const unsigned short* __restrict__ A, int lda,
    const unsigned short* __restrict__ B, int ldb,
    int M, int N, int K,
    const float* __restrict__ bias,
    unsigned short* __restrict__ Cb, int ldc)
{
    constexpr int BROWS  = NB;                    // B tile rows (N-dim)
    constexpr int NI     = NB / 64;               // acc cols per wave (4 or 2)
    constexpr int WCROWS = NB / 4;                // per-wave N span (64 or 32)
    constexpr int SLOTSH = 256 * 32 + BROWS * 32; // shorts per slot
    constexpr int SLOTB  = SLOTSH * 2;            // bytes per slot
    __shared__ __align__(16) unsigned short lds[4 * SLOTSH];

    const int nbn = N / NB;
    int wg = blockIdx.x;
    {   // bijective XCD swizzle (grids are multiples of 8); consecutive wg share bm
        int q = gridDim.x >> 3;
        wg = (wg & 7) * q + (wg >> 3);
    }
    const int bm = wg / nbn, bn = wg % nbn;

    const int t = threadIdx.x;
    const int lane = t & 63, wid = t >> 6;
    const int wr = wid >> 2, wc = wid & 3;        // wave grid 2 x 4
    const int l15 = lane & 15, l4 = lane >> 4;

    // ---- staging source (inverse-swizzled k-slot) ----
    const int sr = t >> 2;                        // row 0..127 within half
    const int ss = (t & 3) ^ ((sr >> 1) & 3);     // pre-swizzled k-slot
    const unsigned short* gA0 = A + (size_t)(bm * 256 + sr) * lda + ss * 8;
    const unsigned short* gA1 = gA0 + (size_t)128 * lda;
    const unsigned short* gB0 = B + (size_t)(bn * NB + sr) * ldb + ss * 8;
    const unsigned short* gB1 = gB0 + (size_t)128 * ldb;  // used only if NB==256

    // ---- swizzled ds_read base byte offsets (within a slot) ----
    const int rsw  = ((l4 ^ ((l15 >> 1) & 3)) << 4);
    const int aoff = (wr * 128 + l15) * 64 + rsw;          // + mi*1024, +4096 for mi>=4
    const int boff = 16384 + (wc * WCROWS + l15) * 64 + rsw;

    f32x4 acc[8][NI];
    const f32x4 z = {0.f, 0.f, 0.f, 0.f};
#pragma unroll
    for (int i = 0; i < 8; i++)
#pragma unroll
        for (int j = 0; j < NI; j++) acc[i][j] = z;

    const int nk = K >> 5;

#define STAGE_A(kt_) do { int s_ = (kt_) & 3;                                              \
        unsigned short* d_ = &lds[s_ * SLOTSH + t * 8];                                    \
        __builtin_amdgcn_global_load_lds((const GLB_AS void*)(gA0 + (size_t)(kt_) * 32),   \
                                         (LDS_AS void*)d_, 16, 0, 0);                      \
        __builtin_amdgcn_global_load_lds((const GLB_AS void*)(gA1 + (size_t)(kt_) * 32),   \
                                         (LDS_AS void*)(d_ + 4096), 16, 0, 0); } while (0)
#define STAGE_B(kt_) do { int s_ = (kt_) & 3;                                              \
        unsigned short* d_ = &lds[s_ * SLOTSH + 8192 + t * 8];                             \
        __builtin_amdgcn_global_load_lds((const GLB_AS void*)(gB0 + (size_t)(kt_) * 32),   \
                                         (LDS_AS void*)d_, 16, 0, 0);                      \
        if (NB == 256)                                                                     \
        __builtin_amdgcn_global_load_lds((const GLB_AS void*)(gB1 + (size_t)(kt_) * 32),   \
                                         (LDS_AS void*)(d_ + 4096), 16, 0, 0); } while (0)

    // ---- prologue: stage tiles 0,1,2 ----
    STAGE_A(0); STAGE_B(0);
    STAGE_A(1); STAGE_B(1);
    STAGE_A(2); STAGE_B(2);
    if (NB == 256) asm volatile("s_waitcnt vmcnt(8)" ::: "memory");   // tile 0 landed
    else           asm volatile("s_waitcnt vmcnt(6)" ::: "memory");
    __builtin_amdgcn_s_barrier();
    __builtin_amdgcn_sched_barrier(0);

    for (int kt = 0; kt < nk; ++kt) {
        const int s = kt & 3;
        const LDS_AS char* ab = (const LDS_AS char*)&lds[0] + s * SLOTB + aoff;
        const LDS_AS char* bb = (const LDS_AS char*)&lds[0] + s * SLOTB + boff;

        // ---------------- phase 0: mi 0..3 ----------------
        bf16x8 af[4], bfr[NI];
#pragma unroll
        for (int i = 0; i < 4; ++i) af[i]  = *(const LDS_AS bf16x8*)(ab + i * 1024);
#pragma unroll
        for (int j = 0; j < NI; ++j) bfr[j] = *(const LDS_AS bf16x8*)(bb + j * 1024);
        if (kt + 3 < nk) STAGE_A(kt + 3);
        __builtin_amdgcn_s_barrier();
        asm volatile("s_waitcnt lgkmcnt(0)" ::: "memory");
        __builtin_amdgcn_sched_barrier(0);
        __builtin_amdgcn_s_setprio(1);
#pragma unroll
        for (int i = 0; i < 4; ++i)
#pragma unroll
            for (int j = 0; j < NI; ++j)
                acc[i][j] = __builtin_amdgcn_mfma_f32_16x16x32_bf16(af[i], bfr[j], acc[i][j], 0, 0, 0);
        __builtin_amdgcn_s_setprio(0);
        __builtin_amdgcn_sched_barrier(0);
        __builtin_amdgcn_s_barrier();

        // ---------------- phase 1: mi 4..7 (B reused) ------
#pragma unroll
        for (int i = 0; i < 4; ++i) af[i] = *(const LDS_AS bf16x8*)(ab + 4096 + i * 1024);
        if (kt + 3 < nk) {
            STAGE_B(kt + 3);
            if (NB == 256) asm volatile("s_waitcnt vmcnt(8)" ::: "memory"); // t+1 landed
            else           asm volatile("s_waitcnt vmcnt(6)" ::: "memory");
        } else {
            asm volatile("s_waitcnt vmcnt(0)" ::: "memory");                // tail drain
        }
        __builtin_amdgcn_s_barrier();
        asm volatile("s_waitcnt lgkmcnt(0)" ::: "memory");
        __builtin_amdgcn_sched_barrier(0);
        __builtin_amdgcn_s_setprio(1);
#pragma unroll
        for (int i = 0; i < 4; ++i)
#pragma unroll
            for (int j = 0; j < NI; ++j)
                acc[4 + i][j] = __builtin_amdgcn_mfma_f32_16x16x32_bf16(af[i], bfr[j], acc[4 + i][j], 0, 0, 0);
        __builtin_amdgcn_s_setprio(0);
        __builtin_amdgcn_sched_barrier(0);
        __builtin_amdgcn_s_barrier();
    }
#undef STAGE_A
#undef STAGE_B

    // ---------------- epilogue ----------------
    const int row0 = bm * 256 + wr * 128;
    const int col0 = bn * NB + wc * WCROWS;
#pragma unroll
    for (int mi = 0; mi < 8; mi++) {
#pragma unroll
        for (int ni = 0; ni < NI; ni++) {
            f32x4 c = acc[mi][ni];
            const int col = col0 + ni * 16 + l15;
            const float bv = bias[col];
#pragma unroll
            for (int r = 0; r < 4; r++) {
                const int row = row0 + mi * 16 + l4 * 4 + r;
                float v = c[r] + bv;
                if (EPI == 0) v = fmaxf(v, 0.f);
                Cb[(size_t)row * ldc + col] = f2bf(v);
            }
        }
    }
}

// ---------------------------------------------------------------- GEMM  C = A @ B^T (m97 128x128)
// EPI: 0 = relu+bias -> bf16; 1 = bias -> bf16; 2 = bias+posenc -> bf16 AND f32; 3 = *scale -> f32
template<int EPI>
__global__ __launch_bounds__(256) void gemm_bt(
    const unsigned short* __restrict__ A, int lda,
    const unsigned short* __restrict__ B, int ldb,
    int M, int N, int K,
    const float* __restrict__ bias,
    unsigned short* __restrict__ Cb, float* __restrict__ Cf, int ldc,
    float scale, const float* __restrict__ dtab)
{
    __shared__ unsigned short ldsA[128 * 32];
    __shared__ unsigned short ldsB[128 * 32];

    const int nbn = N >> 7;
    const int bm = blockIdx.x / nbn, bn = blockIdx.x % nbn;
    const int t = threadIdx.x;
    const int lane = t & 63, wid = t >> 6;
    const int wr = wid >> 1, wc = wid & 1;
    const int l15 = lane & 15, l4 = lane >> 4;

    const unsigned short* ga0 = A + (size_t)(bm * 128 + (t >> 2)) * lda + (t & 3) * 8;
    const unsigned short* gb0 = B + (size_t)(bn * 128 + (t >> 2)) * ldb + (t & 3) * 8;
    const size_t a64 = (size_t)64 * lda, b64 = (size_t)64 * ldb;
    LDS_AS void* laD0 = (LDS_AS void*)(&ldsA[wid * 512]);
    LDS_AS void* laD1 = (LDS_AS void*)(&ldsA[2048 + wid * 512]);
    LDS_AS void* lbD0 = (LDS_AS void*)(&ldsB[wid * 512]);
    LDS_AS void* lbD1 = (LDS_AS void*)(&ldsB[2048 + wid * 512]);

    const bf16x8* pa = (const bf16x8*)&ldsA[(wr * 64 + l15) * 32 + l4 * 8];
    const bf16x8* pb = (const bf16x8*)&ldsB[(wc * 64 + l15) * 32 + l4 * 8];

    f32x4 acc[4][4];
    const f32x4 z = {0.f, 0.f, 0.f, 0.f};
#pragma unroll
    for (int i = 0; i < 4; i++)
#pragma unroll
        for (int j = 0; j < 4; j++) acc[i][j] = z;

    const int nk = K >> 5;
    for (int kt = 0; kt < nk; ++kt) {
        const unsigned short* ga = ga0 + kt * 32;
        const unsigned short* gb = gb0 + kt * 32;
        __builtin_amdgcn_global_load_lds((const GLB_AS void*)ga,         laD0, 16, 0, 0);
        __builtin_amdgcn_global_load_lds((const GLB_AS void*)(ga + a64), laD1, 16, 0, 0);
        __builtin_amdgcn_global_load_lds((const GLB_AS void*)gb,         lbD0, 16, 0, 0);
        __builtin_amdgcn_global_load_lds((const GLB_AS void*)(gb + b64), lbD1, 16, 0, 0);
        __syncthreads();

        bf16x8 af[4], bfr[4];
#pragma unroll
        for (int mi = 0; mi < 4; mi++) af[mi]  = pa[mi * 64];
#pragma unroll
        for (int ni = 0; ni < 4; ni++) bfr[ni] = pb[ni * 64];
#pragma unroll
        for (int mi = 0; mi < 4; mi++)
#pragma unroll
            for (int ni = 0; ni < 4; ni++)
                acc[mi][ni] = __builtin_amdgcn_mfma_f32_16x16x32_bf16(af[mi], bfr[ni], acc[mi][ni], 0, 0, 0);
        __syncthreads();
    }

    const int row0 = bm * 128 + wr * 64;
    const int col0 = bn * 128 + wc * 64;
#pragma unroll
    for (int mi = 0; mi < 4; mi++) {
#pragma unroll
        for (int ni = 0; ni < 4; ni++) {
            f32x4 c = acc[mi][ni];
            const int col = col0 + ni * 16 + l15;
            float bv = 0.f, dv = 0.f;
            if (EPI != 3) bv = bias[col];
            if (EPI == 2) dv = dtab[col >> 1];
#pragma unroll
            for (int r = 0; r < 4; r++) {
                const int row = row0 + mi * 16 + l4 * 4 + r;
                float v = c[r] + bv;
                if (EPI == 0) v = fmaxf(v, 0.f);
                if (EPI == 2) {
                    float ang = (float)row * dv;
                    v += (col & 1) ? cosf(ang) : sinf(ang);
                }
                if (EPI == 3) {
                    Cf[(size_t)row * ldc + col] = v * scale;
                } else {
                    Cb[(size_t)row * ldc + col] = f2bf(v);
                    if (EPI == 2) Cf[(size_t)row * ldc + col] = v;
                }
            }
        }
    }
}

// ---------------------------------------------------------------- v column (fp32)
__global__ __launch_bounds__(256) void vcol_kernel(const float* __restrict__ Hf,
                                                   const float* __restrict__ ipw,
                                                   const float* __restrict__ ipb,
                                                   float* __restrict__ v) {
    const int row = blockIdx.x * 4 + (threadIdx.x >> 6);
    const int lane = threadIdx.x & 63;
    const float* w = ipw + (size_t)1535 * 512;
    const float* h = Hf + (size_t)row * 512;
    float s = 0.f;
    for (int k = lane; k < 512; k += 64) s += h[k] * w[k];
#pragma unroll
    for (int off = 32; off; off >>= 1) s += __shfl_down(s, off);
    if (lane == 0) v[row] = s + ipb[1535];
}

// ---------------------------------------------------------------- attention rows 3584..4095
__global__ __launch_bounds__(256) void attn_rows(const float* __restrict__ S1,
                                                 const float* __restrict__ S2,
                                                 const float* __restrict__ v,
                                                 const float* __restrict__ lamp,
                                                 float* __restrict__ out) {
    const int r = blockIdx.x;
    const int tid = threadIdx.x, lane = tid & 63, wid = tid >> 6;
    const float* s1 = S1 + (size_t)r * 4096;
    const float* s2 = S2 + (size_t)r * 4096;
    __shared__ float red[4][8];

    float m1 = -1e30f, m2 = -1e30f;
    for (int i = tid; i < 4096; i += 256) {
        m1 = fmaxf(m1, s1[i]);
        m2 = fmaxf(m2, s2[i]);
    }
#pragma unroll
    for (int off = 32; off; off >>= 1) {
        m1 = fmaxf(m1, __shfl_down(m1, off));
        m2 = fmaxf(m2, __shfl_down(m2, off));
    }
    if (lane == 0) { red[wid][0] = m1; red[wid][1] = m2; }
    __syncthreads();
    m1 = fmaxf(fmaxf(red[0][0], red[1][0]), fmaxf(red[2][0], red[3][0]));
    m2 = fmaxf(fmaxf(red[0][1], red[1][1]), fmaxf(red[2][1], red[3][1]));

    const int gj = 3584 + r;
    float e1 = 0.f, e2 = 0.f, d1 = 0.f, d2 = 0.f, cs = 0.f;
    for (int i = tid; i < 4096; i += 256) {
        float p1 = expf(s1[i] - m1);
        float p2 = expf(s2[i] - m2);
        float vv = v[i];
        e1 += p1; e2 += p2; d1 += p1 * vv; d2 += p2 * vv;
        if (i > gj) cs += vv;
    }
#pragma unroll
    for (int off = 32; off; off >>= 1) {
        e1 += __shfl_down(e1, off); e2 += __shfl_down(e2, off);
        d1 += __shfl_down(d1, off); d2 += __shfl_down(d2, off);
        cs += __shfl_down(cs, off);
    }
    __syncthreads();
    if (lane == 0) {
        red[wid][0] = e1; red[wid][1] = e2; red[wid][2] = d1; red[wid][3] = d2; red[wid][4] = cs;
    }
    __syncthreads();
    if (tid == 0) {
        e1 = red[0][0] + red[1][0] + red[2][0] + red[3][0];
        e2 = red[0][1] + red[1][1] + red[2][1] + red[3][1];
        d1 = red[0][2] + red[1][2] + red[2][2] + red[3][2];
        d2 = red[0][3] + red[1][3] + red[2][3] + red[3][3];
        cs = red[0][4] + red[1][4] + red[2][4] + red[3][4];
        out[r] = d1 / e1 - lamp[0] * (d2 / e2) + cs;
    }
}

// ---------------------------------------------------------------- fp32 mat-vec, wave per output
template<int RELU>
__global__ __launch_bounds__(256) void matvec(const float* __restrict__ W, const float* __restrict__ x,
                                              const float* __restrict__ b, float* __restrict__ y,
                                              int N, int K) {
    const int o = blockIdx.x * 4 + (threadIdx.x >> 6);
    const int lane = threadIdx.x & 63;
    if (o >= N) return;
    const float* w = W + (size_t)o * K;
    float s = 0.f;
    for (int k = lane; k < K; k += 64) s += w[k] * x[k];
#pragma unroll
    for (int off = 32; off; off >>= 1) s += __shfl_down(s, off);
    if (lane == 0) y[o] = RELU ? fmaxf(s + b[o], 0.f) : (s + b[o]);
}

// ---------------------------------------------------------------- softmax over 256 logits
__global__ __launch_bounds__(256) void softmax256(const float* __restrict__ lg, float* __restrict__ out) {
    const int tid = threadIdx.x, lane = tid & 63, wid = tid >> 6;
    __shared__ float rm[4], rs[4];
    float l = lg[tid];
    float m = l;
#pragma unroll
    for (int off = 32; off; off >>= 1) m = fmaxf(m, __shfl_down(m, off));
    if (lane == 0) rm[wid] = m;
    __syncthreads();
    m = fmaxf(fmaxf(rm[0], rm[1]), fmaxf(rm[2], rm[3]));
    float e = expf(l - m);
    float s = e;
#pragma unroll
    for (int off = 32; off; off >>= 1) s += __shfl_down(s, off);
    if (lane == 0) rs[wid] = s;
    __syncthreads();
    s = rs[0] + rs[1] + rs[2] + rs[3];
    out[tid] = e / s;
}

// ---------------------------------------------------------------- launch
extern "C" void kernel_launch(void* const* d_in, const int* in_sizes, int n_in,
                              void* d_out, int out_size, void* d_ws, size_t ws_size,
                              hipStream_t stream) {
    const float* x      = (const float*)d_in[0];
    const float* enc_w1 = (const float*)d_in[1];
    const float* enc_b1 = (const float*)d_in[2];
    const float* enc_w2 = (const float*)d_in[3];
    const float* enc_b2 = (const float*)d_in[4];
    const float* enc_w3 = (const float*)d_in[5];
    const float* enc_b3 = (const float*)d_in[6];
    const float* enc_w4 = (const float*)d_in[7];
    const float* enc_b4 = (const float*)d_in[8];
    const float* ipw    = (const float*)d_in[9];
    const float* ipb    = (const float*)d_in[10];
    const float* opw    = (const float*)d_in[11];
    const float* opb    = (const float*)d_in[12];
    const float* lam    = (const float*)d_in[13];
    const float* aw1    = (const float*)d_in[14];
    const float* ab1    = (const float*)d_in[15];
    const float* aw2    = (const float*)d_in[16];
    const float* ab2    = (const float*)d_in[17];
    const float* aw3    = (const float*)d_in[18];
    const float* ab3    = (const float*)d_in[19];

    char* ws = (char*)d_ws;
    const size_t MB = 1ull << 20;
    unsigned short* bufA = (unsigned short*)(ws);             // 32MB: Xb then C2b
    unsigned short* bufB = (unsigned short*)(ws + 32 * MB);   // 16MB: C1b then C3b
    float* S1            = (float*)(ws + 32 * MB);            // 8MB (after C3b dead)
    float* S2            = (float*)(ws + 40 * MB);            // 8MB
    unsigned short* Wb   = (unsigned short*)(ws + 48 * MB);   // 16MB: per-layer weight bf16
    unsigned short* IPb  = (unsigned short*)(ws + 64 * MB);   // 1.5MB
    unsigned short* Hb   = (unsigned short*)(ws + 66 * MB);   // 4MB
    float* Hf            = (float*)(ws + 70 * MB);            // 8MB
    unsigned short* Kb   = (unsigned short*)(ws + 78 * MB);   // 4MB
    unsigned short* Qb   = (unsigned short*)(ws + 82 * MB);   // 0.5MB
    float* vcol          = (float*)(ws + 83 * MB);
    float* dtab          = (float*)(ws + 83 * MB + 64 * 1024);
    float* attnv         = (float*)(ws + 83 * MB + 128 * 1024);
    float* hh            = (float*)(ws + 83 * MB + 192 * 1024);
    float* h1            = (float*)(ws + 83 * MB + 256 * 1024);
    float* h2            = (float*)(ws + 83 * MB + 320 * 1024);
    float* lg            = (float*)(ws + 83 * MB + 384 * 1024);

    auto cvt = [&](const float* in, unsigned short* outp, int n) {
        int n4 = n >> 2;
        int blocks = (n4 + 255) / 256;
        if (blocks > 2048) blocks = 2048;
        cvt_f32_bf16<<<dim3(blocks), dim3(256), 0, stream>>>(in, outp, n4);
    };

    divtab_kernel<<<dim3(1), dim3(256), 0, stream>>>(dtab);

    // ---- encoder (bf16 MFMA; big 3 on the 8-phase 256-tile kernel, full grids) ----
    cvt(x, bufA, 4096 * 1024);
    cvt(enc_w1, Wb, 2048 * 1024);
    gemm256_bt<0, 128, 1><<<dim3(16 * 16), dim3(512), 0, stream>>>(bufA, 1024, Wb, 1024,
                                                                   4096, 2048, 1024, enc_b1, bufB, 2048);
    cvt(enc_w2, Wb, 4096 * 2048);
    gemm256_bt<0, 256, 2><<<dim3(16 * 16), dim3(512), 0, stream>>>(bufB, 2048, Wb, 2048,
                                                                   4096, 4096, 2048, enc_b2, bufA, 4096);
    cvt(enc_w3, Wb, 2048 * 4096);
    gemm256_bt<0, 128, 3><<<dim3(16 * 16), dim3(512), 0, stream>>>(bufA, 4096, Wb, 4096,
                                                                   4096, 2048, 4096, enc_b3, bufB, 2048);
    cvt(enc_w4, Wb, 512 * 2048);
    gemm_bt<2><<<dim3(32 * 4), dim3(256), 0, stream>>>(bufB, 2048, Wb, 2048, 4096, 512, 2048,
                                                       enc_b4, Hb, Hf, 512, 1.f, dtab);

    // ---- projections (K full, Q only rows 3584.., v one column) ----
    cvt(ipw, IPb, 1536 * 512);
    gemm_bt<1><<<dim3(32 * 4), dim3(256), 0, stream>>>(Hb, 512, IPb + 512 * 512, 512, 4096, 512, 512,
                                                       ipb + 512, Kb, nullptr, 512, 1.f, nullptr);
    gemm_bt<1><<<dim3(4 * 4), dim3(256), 0, stream>>>(Hb + (size_t)3584 * 512, 512, IPb, 512, 512, 512, 512,
                                                      ipb, Qb, nullptr, 512, 1.f, nullptr);
    vcol_kernel<<<dim3(1024), dim3(256), 0, stream>>>(Hf, ipw, ipb, vcol);

    // ---- scores (512 x 4096, two heads) ----
    const float rs2 = 0.70710678118654752f;
    gemm_bt<3><<<dim3(4 * 32), dim3(256), 0, stream>>>(Qb, 512, Kb, 512, 512, 4096, 256,
                                                       nullptr, nullptr, S1, 4096, rs2, nullptr);
    gemm_bt<3><<<dim3(4 * 32), dim3(256), 0, stream>>>(Qb + 256, 512, Kb + 256, 512, 512, 4096, 256,
                                                       nullptr, nullptr, S2, 4096, rs2, nullptr);

    // ---- softmax + diff + causal + v-dot ----
    attn_rows<<<dim3(512), dim3(256), 0, stream>>>(S1, S2, vcol, lam, attnv);

    // ---- fp32 tail (single row) ----
    matvec<0><<<dim3(128), dim3(256), 0, stream>>>(opw, attnv, opb, hh, 512, 512);
    matvec<1><<<dim3(256), dim3(256), 0, stream>>>(aw1, hh, ab1, h1, 1024, 512);
    matvec<1><<<dim3(512), dim3(256), 0, stream>>>(aw2, h1, ab2, h2, 2048, 1024);
    matvec<0><<<dim3(64), dim3(256), 0, stream>>>(aw3, h2, ab3, lg, 256, 2048);
    softmax256<<<dim3(1), dim3(256), 0, stream>>>(lg, (float*)d_out);
}